// Round 1
// baseline (27.286 us; speedup 1.0000x reference)
//
#include <hip/hip_runtime.h>

#define N_NODES_C 50000
#define N_EDGES_C 600000
#define DIM 128
#define NCLS 2

// ---------------------------------------------------------------------------
// Phase 1: per-node projections.
//   P[n][c] = dot(h[n], W[c][0:128])   + b[c]   (b folded here, once per node)
//   Q[n][c] = dot(h[n], W[c][128:256])
// One wave (64 lanes) per node: lane loads float2 of the row (coalesced
// 512 B/row), computes 4 partial dots, butterfly-reduces across 64 lanes.
// ---------------------------------------------------------------------------
__global__ __launch_bounds__(256) void node_proj_kernel(
    const float* __restrict__ h, const float* __restrict__ W,
    const float* __restrict__ b, float* __restrict__ P, float* __restrict__ Q)
{
    const int wave = blockIdx.x * (blockDim.x >> 6) + (threadIdx.x >> 6);
    const int lane = threadIdx.x & 63;
    if (wave >= N_NODES_C) return;

    const float2 hv  = *reinterpret_cast<const float2*>(h + (size_t)wave * DIM + lane * 2);
    const float2 wu0 = *reinterpret_cast<const float2*>(W + 0 * 2 * DIM +       lane * 2);
    const float2 wv0 = *reinterpret_cast<const float2*>(W + 0 * 2 * DIM + DIM + lane * 2);
    const float2 wu1 = *reinterpret_cast<const float2*>(W + 1 * 2 * DIM +       lane * 2);
    const float2 wv1 = *reinterpret_cast<const float2*>(W + 1 * 2 * DIM + DIM + lane * 2);

    float su0 = hv.x * wu0.x + hv.y * wu0.y;
    float su1 = hv.x * wu1.x + hv.y * wu1.y;
    float sv0 = hv.x * wv0.x + hv.y * wv0.y;
    float sv1 = hv.x * wv1.x + hv.y * wv1.y;

    #pragma unroll
    for (int off = 32; off > 0; off >>= 1) {
        su0 += __shfl_xor(su0, off, 64);
        su1 += __shfl_xor(su1, off, 64);
        sv0 += __shfl_xor(sv0, off, 64);
        sv1 += __shfl_xor(sv1, off, 64);
    }

    if (lane == 0) {
        *reinterpret_cast<float2*>(P + (size_t)wave * 2) = make_float2(su0 + b[0], su1 + b[1]);
        *reinterpret_cast<float2*>(Q + (size_t)wave * 2) = make_float2(sv0, sv1);
    }
}

// ---------------------------------------------------------------------------
// Phase 2: per-edge gather-add. 8 B gathered from each of P and Q (L2-hot,
// tables total 800 KB < 4 MB per-XCD L2), coalesced float2 store.
// ---------------------------------------------------------------------------
__global__ __launch_bounds__(256) void edge_score_kernel(
    const int* __restrict__ src, const int* __restrict__ dst,
    const float* __restrict__ P, const float* __restrict__ Q,
    float* __restrict__ out)
{
    const int stride = gridDim.x * blockDim.x;
    for (int e = blockIdx.x * blockDim.x + threadIdx.x; e < N_EDGES_C; e += stride) {
        const int s = src[e];
        const int d = dst[e];
        const float2 p = *reinterpret_cast<const float2*>(P + (size_t)s * 2);
        const float2 q = *reinterpret_cast<const float2*>(Q + (size_t)d * 2);
        *reinterpret_cast<float2*>(out + (size_t)e * 2) = make_float2(p.x + q.x, p.y + q.y);
    }
}

// ---------------------------------------------------------------------------
// Fallback (only if workspace is unexpectedly tiny): one wave per edge,
// direct gather of h rows + wave reduce. Correct but ~30x more traffic.
// ---------------------------------------------------------------------------
__global__ __launch_bounds__(256) void edge_direct_kernel(
    const float* __restrict__ h, const float* __restrict__ W,
    const float* __restrict__ b,
    const int* __restrict__ src, const int* __restrict__ dst,
    float* __restrict__ out)
{
    const int wave = blockIdx.x * (blockDim.x >> 6) + (threadIdx.x >> 6);
    const int lane = threadIdx.x & 63;
    if (wave >= N_EDGES_C) return;

    const int s = src[wave];
    const int d = dst[wave];
    const float2 hu = *reinterpret_cast<const float2*>(h + (size_t)s * DIM + lane * 2);
    const float2 hv = *reinterpret_cast<const float2*>(h + (size_t)d * DIM + lane * 2);
    const float2 wu0 = *reinterpret_cast<const float2*>(W + 0 * 2 * DIM +       lane * 2);
    const float2 wv0 = *reinterpret_cast<const float2*>(W + 0 * 2 * DIM + DIM + lane * 2);
    const float2 wu1 = *reinterpret_cast<const float2*>(W + 1 * 2 * DIM +       lane * 2);
    const float2 wv1 = *reinterpret_cast<const float2*>(W + 1 * 2 * DIM + DIM + lane * 2);

    float s0 = hu.x * wu0.x + hu.y * wu0.y + hv.x * wv0.x + hv.y * wv0.y;
    float s1 = hu.x * wu1.x + hu.y * wu1.y + hv.x * wv1.x + hv.y * wv1.y;

    #pragma unroll
    for (int off = 32; off > 0; off >>= 1) {
        s0 += __shfl_xor(s0, off, 64);
        s1 += __shfl_xor(s1, off, 64);
    }
    if (lane == 0) {
        *reinterpret_cast<float2*>(out + (size_t)wave * 2) = make_float2(s0 + b[0], s1 + b[1]);
    }
}

extern "C" void kernel_launch(void* const* d_in, const int* in_sizes, int n_in,
                              void* d_out, int out_size, void* d_ws, size_t ws_size,
                              hipStream_t stream) {
    const float* h   = (const float*)d_in[0];
    const float* W   = (const float*)d_in[1];
    const float* b   = (const float*)d_in[2];
    const int*   src = (const int*)d_in[3];
    const int*   dst = (const int*)d_in[4];
    float* out = (float*)d_out;

    const size_t needed = (size_t)N_NODES_C * 2 * sizeof(float) * 2;  // P + Q = 800 KB

    if (ws_size >= needed) {
        float* P = (float*)d_ws;
        float* Q = P + (size_t)N_NODES_C * 2;

        // Phase 1: 4 waves/block -> 4 nodes/block
        const int nodes_per_block = 256 / 64;
        const int grid1 = (N_NODES_C + nodes_per_block - 1) / nodes_per_block;
        node_proj_kernel<<<grid1, 256, 0, stream>>>(h, W, b, P, Q);

        // Phase 2: one thread per edge
        const int grid2 = (N_EDGES_C + 255) / 256;
        edge_score_kernel<<<grid2, 256, 0, stream>>>(src, dst, P, Q, out);
    } else {
        const int edges_per_block = 256 / 64;
        const int grid = (N_EDGES_C + edges_per_block - 1) / edges_per_block;
        edge_direct_kernel<<<grid, 256, 0, stream>>>(h, W, b, src, dst, out);
    }
}

// Round 2
// 19.451 us; speedup vs baseline: 1.4028x; 1.4028x over previous
//
#include <hip/hip_runtime.h>

#define N_NODES_C 50000
#define N_EDGES_C 600000
#define DIM 128
#define NCLS 2

// ---------------------------------------------------------------------------
// Phase 1: per-node projections, 16 lanes per node (4 nodes/wave).
//   P[n][c] = dot(h[n], W[c][0:128]) + b[c]
//   Q[n][c] = dot(h[n], W[c][128:256])
// Lane (sub = lane&15) loads h[node*128 + sub*8 .. +7] as two float4s
// (wave reads 4 consecutive rows = 2 KB contiguous, fully coalesced).
// Butterfly reduce over 16 lanes: 4 steps x 4 accumulators.
// ---------------------------------------------------------------------------
__global__ __launch_bounds__(256) void node_proj_kernel(
    const float* __restrict__ h, const float* __restrict__ W,
    const float* __restrict__ b, float* __restrict__ P, float* __restrict__ Q)
{
    const int wave = blockIdx.x * (blockDim.x >> 6) + (threadIdx.x >> 6);
    const int lane = threadIdx.x & 63;
    const int sub  = lane & 15;
    const int node = wave * 4 + (lane >> 4);
    if (node >= N_NODES_C) return;

    const float4* hrow = reinterpret_cast<const float4*>(h + (size_t)node * DIM);
    const float4 a0 = hrow[sub * 2];
    const float4 a1 = hrow[sub * 2 + 1];

    const float4* Wu0 = reinterpret_cast<const float4*>(W + 0 * 2 * DIM);
    const float4* Wv0 = reinterpret_cast<const float4*>(W + 0 * 2 * DIM + DIM);
    const float4* Wu1 = reinterpret_cast<const float4*>(W + 1 * 2 * DIM);
    const float4* Wv1 = reinterpret_cast<const float4*>(W + 1 * 2 * DIM + DIM);

    const float4 u0a = Wu0[sub * 2], u0b = Wu0[sub * 2 + 1];
    const float4 v0a = Wv0[sub * 2], v0b = Wv0[sub * 2 + 1];
    const float4 u1a = Wu1[sub * 2], u1b = Wu1[sub * 2 + 1];
    const float4 v1a = Wv1[sub * 2], v1b = Wv1[sub * 2 + 1];

    float su0 = a0.x*u0a.x + a0.y*u0a.y + a0.z*u0a.z + a0.w*u0a.w
              + a1.x*u0b.x + a1.y*u0b.y + a1.z*u0b.z + a1.w*u0b.w;
    float sv0 = a0.x*v0a.x + a0.y*v0a.y + a0.z*v0a.z + a0.w*v0a.w
              + a1.x*v0b.x + a1.y*v0b.y + a1.z*v0b.z + a1.w*v0b.w;
    float su1 = a0.x*u1a.x + a0.y*u1a.y + a0.z*u1a.z + a0.w*u1a.w
              + a1.x*u1b.x + a1.y*u1b.y + a1.z*u1b.z + a1.w*u1b.w;
    float sv1 = a0.x*v1a.x + a0.y*v1a.y + a0.z*v1a.z + a0.w*v1a.w
              + a1.x*v1b.x + a1.y*v1b.y + a1.z*v1b.z + a1.w*v1b.w;

    #pragma unroll
    for (int off = 8; off > 0; off >>= 1) {
        su0 += __shfl_xor(su0, off, 64);
        su1 += __shfl_xor(su1, off, 64);
        sv0 += __shfl_xor(sv0, off, 64);
        sv1 += __shfl_xor(sv1, off, 64);
    }

    if (sub == 0) {
        *reinterpret_cast<float2*>(P + (size_t)node * 2) = make_float2(su0 + b[0], su1 + b[1]);
        *reinterpret_cast<float2*>(Q + (size_t)node * 2) = make_float2(sv0, sv1);
    }
}

// ---------------------------------------------------------------------------
// Phase 2: per-edge gather-add, 2 edges per thread.
// int2 index loads, 4x 8B gathers (P/Q tables = 800 KB, L2-resident),
// one coalesced float4 store per thread.
// ---------------------------------------------------------------------------
__global__ __launch_bounds__(256) void edge_score_kernel(
    const int* __restrict__ src, const int* __restrict__ dst,
    const float* __restrict__ P, const float* __restrict__ Q,
    float* __restrict__ out)
{
    const int npairs = N_EDGES_C / 2;
    const int i = blockIdx.x * blockDim.x + threadIdx.x;
    if (i >= npairs) return;

    const int2 s = reinterpret_cast<const int2*>(src)[i];
    const int2 d = reinterpret_cast<const int2*>(dst)[i];

    const float2 p0 = *reinterpret_cast<const float2*>(P + (size_t)s.x * 2);
    const float2 q0 = *reinterpret_cast<const float2*>(Q + (size_t)d.x * 2);
    const float2 p1 = *reinterpret_cast<const float2*>(P + (size_t)s.y * 2);
    const float2 q1 = *reinterpret_cast<const float2*>(Q + (size_t)d.y * 2);

    float4 r;
    r.x = p0.x + q0.x;
    r.y = p0.y + q0.y;
    r.z = p1.x + q1.x;
    r.w = p1.y + q1.y;
    reinterpret_cast<float4*>(out)[i] = r;
}

extern "C" void kernel_launch(void* const* d_in, const int* in_sizes, int n_in,
                              void* d_out, int out_size, void* d_ws, size_t ws_size,
                              hipStream_t stream) {
    const float* h   = (const float*)d_in[0];
    const float* W   = (const float*)d_in[1];
    const float* b   = (const float*)d_in[2];
    const int*   src = (const int*)d_in[3];
    const int*   dst = (const int*)d_in[4];
    float* out = (float*)d_out;

    float* P = (float*)d_ws;
    float* Q = P + (size_t)N_NODES_C * 2;

    // Phase 1: 16 nodes per 256-thread block (4 waves x 4 nodes)
    const int nodes_per_block = 16;
    const int grid1 = (N_NODES_C + nodes_per_block - 1) / nodes_per_block;
    node_proj_kernel<<<grid1, 256, 0, stream>>>(h, W, b, P, Q);

    // Phase 2: 2 edges per thread
    const int npairs = N_EDGES_C / 2;
    const int grid2 = (npairs + 255) / 256;
    edge_score_kernel<<<grid2, 256, 0, stream>>>(src, dst, P, Q, out);
}